// Round 9
// baseline (218.758 us; speedup 1.0000x reference)
//
#include <hip/hip_runtime.h>

// Problem constants (reference: H = W = 2048, C = 8, N = 1e6)
#define HH 2048
#define WW 2048
#define CC 8
#define MODV 2044.0f   // H - 4

typedef float f32x2 __attribute__((ext_vector_type(2)));
typedef float f32x4 __attribute__((ext_vector_type(4)));

// Cooperative gather (4 lanes/point) x 4 points/group.
//
// Measured walls (R0-R7):
//  - CU line-transaction path: ~5.9 cyc per 64B-line transaction per CU
//    (fits direct 80us, binned 94-100us). Coop 4-lane chunked loads merge
//    same-line lanes -> CU-path cost ~21-27 cyc/pt (no longer binding;
//    R7 measured 69us vs no-merge floor of ~85us).
//  - HBM random-64B rate: coop measured 192MB/69us = 2.78 TB/s (binding).
//    R1 showed this rate rises with outstanding-request depth (2.45->2.72
//    TB/s at 2x MLP). This version quadruples gather instructions in
//    flight: 4 points/group, 8 gathers back-to-back, sched_barrier(0)
//    fence so the compiler cannot serialize-and-reuse destinations
//    (R2 lesson: VGPR_Count 24-28 proved silent serialization).
//
// Per-point math (reference naming: tl=V[i0][i1], tr=V[i0+1][i1],
// bl=V[i0][i1+1], br=V[i0+1][i1+1]; mt = tr + d0*(tl-tr),
// mb = br + d0*(bl-br), out = mb + d1*(mt-mb)):
//   row i0 holds [tl|bl] (64B contiguous), row i0+1 holds [tr|br].
//   lane c = tid&3 loads 16B chunk c of each row segment;
//   v = row1 + d0*(row0 - row1) gives mt on lanes c<2, mb on c>=2;
//   shfl_xor(v,2) swaps mt<->mb within the group (partners always share
//   the same point -> uniformly active, including tails);
//   lanes c<2 store out chunk c (contiguous 32B per group -> coalesced).

struct PrepP {
    float d0, d1, m;
    const float* p;      // &V[i0][i1] + c*4  (chunk c of row-i0 segment)
};

__device__ __forceinline__ PrepP prep_point(f32x2 co, const float* visible, int c) {
    PrepP r;
    // c = (coord - 1) mod 2044 + 1 (floored mod, positive divisor)
    float cx = fmodf(co.x - 1.0f, MODV); if (cx < 0.0f) cx += MODV; cx += 1.0f;
    float cy = fmodf(co.y - 1.0f, MODV); if (cy < 0.0f) cy += MODV; cy += 1.0f;
    float fx = floorf(cx);
    float fy = floorf(cy);
    r.d0 = cx - fx;              // delta along dim 0 (rows)
    r.d1 = cy - fy;              // delta along dim 1 (cols)
    int i0 = (int)fx;            // row in [1, 2044]
    int i1 = (int)fy;            // col in [1, 2044] (i1+1 <= 2045 < 2048)
    // off = c > dims (unreachable since c < 2045; kept for fidelity)
    r.m = (cx > (float)HH) ? 0.0f : 1.0f;
    r.p = visible + ((size_t)i0 * WW + (size_t)i1) * CC + c * 4;
    return r;
}

__device__ __forceinline__ void finish_point(f32x4 r0, f32x4 r1, PrepP P,
                                             float* __restrict__ out,
                                             size_t point, bool live, int c) {
    // d0-lerp: mt on lanes c<2, mb on lanes c>=2 (same formula)
    f32x4 v = r1 + P.d0 * (r0 - r1);
    f32x4 w;
    w.x = __shfl_xor(v.x, 2, 64);
    w.y = __shfl_xor(v.y, 2, 64);
    w.z = __shfl_xor(v.z, 2, 64);
    w.w = __shfl_xor(v.w, 2, 64);
    if (live && c < 2) {
        // v = mt chunk, w = mb chunk; out = mb + d1*(mt - mb)
        f32x4 o = P.m * (w + P.d1 * (v - w));
        *(f32x4*)(out + point * CC + c * 4) = o;
    }
}

__global__ __launch_bounds__(256) void idx2pixel_coop4(
    const float* __restrict__ coords,   // (N, 2)
    const float* __restrict__ visible,  // (H, W, C) row-major
    float* __restrict__ out,            // (N, C)
    int n)
{
    int tid = blockIdx.x * 256 + threadIdx.x;
    int g = tid >> 2;              // group id = point-slot A
    int c = threadIdx.x & 3;       // 16B chunk within the 64B row segment
    int q = (n + 3) >> 2;
    if (g >= q) return;            // group-uniform exit

    int ptB = g + q, ptC = g + 2 * q, ptD = g + 3 * q;
    bool hB = ptB < n, hC = ptC < n, hD = ptD < n;
    int ixB = hB ? ptB : g;        // clamp masked points to safe addresses
    int ixC = hC ? ptC : g;
    int ixD = hD ? ptD : g;

    const f32x2* cp = reinterpret_cast<const f32x2*>(coords);
    f32x2 coA = cp[g];
    f32x2 coB = cp[ixB];
    f32x2 coC = cp[ixC];
    f32x2 coD = cp[ixD];

    PrepP A = prep_point(coA, visible, c);
    PrepP B = prep_point(coB, visible, c);
    PrepP C = prep_point(coC, visible, c);
    PrepP D = prep_point(coD, visible, c);

    const size_t RS = (size_t)WW * CC;   // row stride in floats

    // ---- 8 gathers issued back-to-back; fence keeps them clustered ----
    f32x4 rA0 = *(const f32x4*)(A.p);        // row i0:   [tl|bl] chunk c
    f32x4 rA1 = *(const f32x4*)(A.p + RS);   // row i0+1: [tr|br] chunk c
    f32x4 rB0 = *(const f32x4*)(B.p);
    f32x4 rB1 = *(const f32x4*)(B.p + RS);
    f32x4 rC0 = *(const f32x4*)(C.p);
    f32x4 rC1 = *(const f32x4*)(C.p + RS);
    f32x4 rD0 = *(const f32x4*)(D.p);
    f32x4 rD1 = *(const f32x4*)(D.p + RS);

    __builtin_amdgcn_sched_barrier(0);   // nothing crosses: 8 loads in flight

    // ---- combine + store per point, in issue order ----
    finish_point(rA0, rA1, A, out, (size_t)g,   true, c);
    finish_point(rB0, rB1, B, out, (size_t)ptB, hB,   c);
    finish_point(rC0, rC1, C, out, (size_t)ptC, hC,   c);
    finish_point(rD0, rD1, D, out, (size_t)ptD, hD,   c);
}

extern "C" void kernel_launch(void* const* d_in, const int* in_sizes, int n_in,
                              void* d_out, int out_size, void* d_ws, size_t ws_size,
                              hipStream_t stream) {
    const float* coords  = (const float*)d_in[0];  // (N, 2) fp32
    const float* visible = (const float*)d_in[1];  // (2048, 2048, 8) fp32
    float* out = (float*)d_out;                    // (N, 8) fp32
    int n = in_sizes[0] / 2;

    // 4 lanes per point, 4 points per group -> 64 points per 256-thread block
    int q = (n + 3) >> 2;          // groups needed
    int grid = (q + 63) / 64;      // 64 groups per block
    idx2pixel_coop4<<<grid, 256, 0, stream>>>(coords, visible, out, n);
}

// Round 10
// 215.217 us; speedup vs baseline: 1.0165x; 1.0165x over previous
//
#include <hip/hip_runtime.h>

// Problem constants (reference: H = W = 2048, C = 8, N = 1e6)
#define HH 2048
#define WW 2048
#define CC 8
#define MODV 2044.0f   // H - 4

typedef float f32x2 __attribute__((ext_vector_type(2)));
typedef float f32x4 __attribute__((ext_vector_type(4)));

// Cooperative gather: 4 lanes per point. (Session-best structure, R7: 69us
// kernel-side, total 216.2us.)
//
// Why this is the roofline (R0-R9 evidence):
//  - CU line-transaction path ~5.9 cyc/64B-line/CU (fits direct 80us,
//    binned 94-100us). 4-lane chunked loads merge same-line lanes ->
//    CU-path ~21 cyc/pt, no longer binding.
//  - Binding wall: downstream random-line service rate ~2.8 TB/s
//    (192 MB / 69us). Falsifiers closed: 4x request depth flat (R9);
//    L2-resident binning raised time despite FETCH 161->70 MB (R4/R5);
//    remaining 2 gather transactions/pt are compulsory (row segments 8KB
//    apart; stores already full-line; coords amortized).
//
// Math (reference naming: tl=V[i0][i1], tr=V[i0+1][i1], bl=V[i0][i1+1],
// br=V[i0+1][i1+1]; mt = tr + d0*(tl-tr), mb = br + d0*(bl-br),
// out = mb + d1*(mt-mb)):
//   row i0 holds [tl|bl] (64B contiguous), row i0+1 holds [tr|br].
//   lane c = tid&3 loads 16B chunk c of each row segment;
//   v = row1 + d0*(row0-row1) gives mt on lanes c<2, mb on c>=2;
//   shfl_xor(v,2) swaps mt<->mb between partner lanes (partners share the
//   same point -> uniformly active, including tail waves);
//   lanes c<2 store out chunk c (32 active lanes, contiguous 512B/wave).
__global__ __launch_bounds__(256) void idx2pixel_coop(
    const float* __restrict__ coords,   // (N, 2)
    const float* __restrict__ visible,  // (H, W, C) row-major
    float* __restrict__ out,            // (N, C)
    int n)
{
    int tid = blockIdx.x * 256 + threadIdx.x;
    int point = tid >> 2;          // one point per 4-lane group
    int c = threadIdx.x & 3;       // chunk within the 64B row segment
    if (point >= n) return;        // partner lanes share `point`: uniform exit

    // 4 lanes read the same 8B -> merges to one line-transaction per 2 groups
    f32x2 co = reinterpret_cast<const f32x2*>(coords)[point];

    // c = (coord - 1) mod 2044 + 1 (floored mod, positive divisor)
    float cx = fmodf(co.x - 1.0f, MODV); if (cx < 0.0f) cx += MODV; cx += 1.0f;
    float cy = fmodf(co.y - 1.0f, MODV); if (cy < 0.0f) cy += MODV; cy += 1.0f;
    float fx = floorf(cx);
    float fy = floorf(cy);
    float d0 = cx - fx;            // delta along dim 0 (rows)
    float d1 = cy - fy;            // delta along dim 1 (cols)
    int i0 = (int)fx;              // row in [1, 2044]
    int i1 = (int)fy;              // col in [1, 2044] (i1+1 <= 2045 < 2048)
    // off = c > dims (unreachable since c < 2045; kept for fidelity)
    float m = (cx > (float)HH) ? 0.0f : 1.0f;

    const float* p = visible + ((size_t)i0 * WW + (size_t)i1) * CC + c * 4;
    f32x4 rA = *(const f32x4*)(p);                      // row i0:   [tl|bl] chunk c
    f32x4 rB = *(const f32x4*)(p + (size_t)WW * CC);    // row i0+1: [tr|br] chunk c

    // d0-lerp: mt on lanes c<2, mb on lanes c>=2 (same formula)
    f32x4 v = rB + d0 * (rA - rB);

    // partner (c^2) delivers the other mid for the same channels
    f32x4 w;
    w.x = __shfl_xor(v.x, 2, 64);
    w.y = __shfl_xor(v.y, 2, 64);
    w.z = __shfl_xor(v.z, 2, 64);
    w.w = __shfl_xor(v.w, 2, 64);

    if (c < 2) {
        // v = mt chunk, w = mb chunk; out = mb + d1*(mt - mb)
        f32x4 o = m * (w + d1 * (v - w));
        *(f32x4*)(out + (size_t)point * CC + c * 4) = o;
    }
}

extern "C" void kernel_launch(void* const* d_in, const int* in_sizes, int n_in,
                              void* d_out, int out_size, void* d_ws, size_t ws_size,
                              hipStream_t stream) {
    const float* coords  = (const float*)d_in[0];  // (N, 2) fp32
    const float* visible = (const float*)d_in[1];  // (2048, 2048, 8) fp32
    float* out = (float*)d_out;                    // (N, 8) fp32
    int n = in_sizes[0] / 2;

    // 4 threads per point, 64 points per 256-thread block
    int grid = (n + 63) / 64;
    idx2pixel_coop<<<grid, 256, 0, stream>>>(coords, visible, out, n);
}